// Round 11
// baseline (54.821 us; speedup 1.0000x reference)
//
#include <hip/hip_runtime.h>
#include <math.h>

#define NUM_CLASSES 5
constexpr int B = 2, C = 64, D = 32, H = 64, W = 64;
constexpr int V = D * H * W;          // 131072
constexpr int TD = 16, TH = 32, TW = 32;
constexpr int TVOX = TD * TH * TW;    // 16384
constexpr float EPS_COS = 1e-8f;

typedef float f32x4 __attribute__((ext_vector_type(4)));
typedef float f32x2 __attribute__((ext_vector_type(2)));

// workspace layout (float offsets). Sums slotted per q-octant:
// ((b*K+k)*C+c)*8+q — plain stores, no zeroing. Counts cancel in cosine.
constexpr int OFF_SUMS_S = 0;                      // 640*8
constexpr int OFF_SUMS_T = 5120;                   // 640*8
constexpr int OFF_LOSS   = 10240;
constexpr int OFF_TICKET = 10241;                  // int (zeroed by sums)
constexpr int WS_FLOATS  = 10256;

// non-temporal loads: bypass the MALL-allocation path. Measured (r5-r10):
// cached cold reads cap ~3 TB/s; nt scales with BOTH footprint (>=4KB
// contiguous plane-visits; 2KB collapses) and wave concurrency (sums
// 16->32 waves/CU: 5.4 -> 5.8 TB/s). Per-thread load depth: irrelevant
// (proven null 3x). r9: hipLaunchCooperativeKernel silently no-ops under
// graph capture — fusion unavailable.
__device__ __forceinline__ f32x4 ntload4(const float* p) {
    return __builtin_nontemporal_load(reinterpret_cast<const f32x4*>(p));
}
__device__ __forceinline__ float ntload1(const float* p) {
    return __builtin_nontemporal_load(p);
}

// per-(b,c) per-class sums. grid: (8, B*C) = 1024 blocks, 512 threads,
// 4 blocks/CU (32 waves/CU, chip max). FROZEN from r10 (~23 us, 5.8 TB/s).
__global__ __launch_bounds__(512, 8) void sums_kernel(
    const float* __restrict__ fS, const float* __restrict__ fT,
    const int* __restrict__ tgt, float* __restrict__ ws)
{
    const int bc = blockIdx.y;           // 0..127
    const int b = bc >> 6, c = bc & 63;
    const int q = blockIdx.x;            // octant 0..7
    const int tid = threadIdx.x;         // 0..511

    float accS[NUM_CLASSES] = {0, 0, 0, 0, 0};
    float accT[NUM_CLASSES] = {0, 0, 0, 0, 0};

#pragma unroll
    for (int it = 0; it < 2; ++it) {     // 8192 voxels = one tz plane each
        const int* tb = tgt + b * TVOX + (q * 2 + it) * (TH * TW) + (tid & 15) * 2;
        int2 L0 = *reinterpret_cast<const int2*>(tb + (tid >> 5) * TW);
        int2 L1 = *reinterpret_cast<const int2*>(tb + (16 + (tid >> 5)) * TW);

        const long base = (long)bc * V + q * 16384 + it * 8192 + tid * 4;
        f32x4 s0 = ntload4(fS + base);
        f32x4 s1 = ntload4(fS + base + 2048);
        f32x4 s2 = ntload4(fS + base + 4096);
        f32x4 s3 = ntload4(fS + base + 6144);
        f32x4 t0 = ntload4(fT + base);
        f32x4 t1 = ntload4(fT + base + 2048);
        f32x4 t2 = ntload4(fT + base + 4096);
        f32x4 t3 = ntload4(fT + base + 6144);

        float sA01 = (s0.x + s0.y) + (s2.x + s2.y), sA23 = (s0.z + s0.w) + (s2.z + s2.w);
        float sB01 = (s1.x + s1.y) + (s3.x + s3.y), sB23 = (s1.z + s1.w) + (s3.z + s3.w);
        float tA01 = (t0.x + t0.y) + (t2.x + t2.y), tA23 = (t0.z + t0.w) + (t2.z + t2.w);
        float tB01 = (t1.x + t1.y) + (t3.x + t3.y), tB23 = (t1.z + t1.w) + (t3.z + t3.w);
#pragma unroll
        for (int k = 0; k < NUM_CLASSES; ++k) {     // static indices only
            accS[k] += ((L0.x == k) ? sA01 : 0.0f) + ((L0.y == k) ? sA23 : 0.0f)
                     + ((L1.x == k) ? sB01 : 0.0f) + ((L1.y == k) ? sB23 : 0.0f);
            accT[k] += ((L0.x == k) ? tA01 : 0.0f) + ((L0.y == k) ? tA23 : 0.0f)
                     + ((L1.x == k) ? tB01 : 0.0f) + ((L1.y == k) ? tB23 : 0.0f);
        }
    }

    __shared__ float wsum[8][2 * NUM_CLASSES];
    int lane = tid & 63, wid = tid >> 6;
#pragma unroll
    for (int k = 0; k < NUM_CLASSES; ++k) {
        float vS = accS[k], vT = accT[k];
        for (int off = 32; off; off >>= 1) {
            vS += __shfl_down(vS, off);
            vT += __shfl_down(vT, off);
        }
        if (lane == 0) { wsum[wid][k] = vS; wsum[wid][NUM_CLASSES + k] = vT; }
    }
    __syncthreads();
    if (tid < 2 * NUM_CLASSES) {
        float v = 0.0f;
#pragma unroll
        for (int w = 0; w < 8; ++w) v += wsum[w][tid];
        int k = tid % NUM_CLASSES;
        int base = (tid < NUM_CLASSES) ? OFF_SUMS_S : OFF_SUMS_T;
        ws[base + ((b * NUM_CLASSES + k) * C + c) * 8 + q] = v;   // slotted store
    }
    // zero LOSS + ticket for the (stream-ordered) loss pass
    if (q == 0 && bc == 0 && tid >= 2 * NUM_CLASSES && tid < 2 * NUM_CLASSES + 2)
        ws[OFF_LOSS + (tid - 2 * NUM_CLASSES)] = 0.0f;
}

// per-voxel cosine + loss reduce + finalize. r11 change: 1024 threads,
// 1 voxel/thread (was 512 thr x 2 vox) — same 1024-voxel window, same 4KB
// plane-visits, same 256 blocks; wave concurrency 8 -> 16 waves/CU.
__global__ __launch_bounds__(1024) void loss_kernel(
    const float* __restrict__ fS, const float* __restrict__ fT,
    const int* __restrict__ tgt, float* __restrict__ ws, float* __restrict__ out)
{
    __shared__ float mST[C * NUM_CLASSES * 2];   // [c][k][{S,T}] raw sums
    __shared__ float nrm[2][8];
    __shared__ float red[16];
    int tid = threadIdx.x;
    int b = blockIdx.y;

    if (tid < C * NUM_CLASSES) {
        int i = tid;
        int c = i / NUM_CLASSES, k = i % NUM_CLASSES;
        int wi = ((b * NUM_CLASSES + k) * C + c) * 8;
        float sS = 0.0f, sT = 0.0f;
#pragma unroll
        for (int qq = 0; qq < 8; ++qq) {
            sS += ws[OFF_SUMS_S + wi + qq];
            sT += ws[OFF_SUMS_T + wi + qq];
        }
        mST[i * 2]     = sS;
        mST[i * 2 + 1] = sT;
    }
    __syncthreads();
    if (tid < 2 * NUM_CLASSES) {                 // 10 center-direction norms
        int k = tid % NUM_CLASSES;
        int st = tid / NUM_CLASSES;              // 0=S, 1=T
        float s = 0.0f;
        for (int c = 0; c < C; ++c) { float v = mST[(c * NUM_CLASSES + k) * 2 + st]; s += v * v; }
        nrm[st][k] = sqrtf(s);
    }
    __syncthreads();

    int v = blockIdx.x * 1024 + tid;             // one voxel per thread
    int z = v >> 12, y = (v >> 6) & 63, x = v & 63;
    int k = tgt[b * TVOX + (z >> 1) * (TH * TW) + (y >> 1) * TW + (x >> 1)];

    const float* pS = fS + (long)b * C * V + v;
    const float* pT = fT + (long)b * C * V + v;
    float dS = 0, qS = 0, dT = 0, qT = 0;

    for (int cb = 0; cb < C; cb += 16) {
        float a[16], t[16];
#pragma unroll
        for (int j = 0; j < 16; ++j) a[j] = ntload1(pS + (long)(cb + j) * V);
#pragma unroll
        for (int j = 0; j < 16; ++j) t[j] = ntload1(pT + (long)(cb + j) * V);
#pragma unroll
        for (int j = 0; j < 16; ++j) {
            float2 m = *reinterpret_cast<const float2*>(&mST[((cb + j) * NUM_CLASSES + k) * 2]);
            dS += a[j] * m.x; qS += a[j] * a[j];
            dT += t[j] * m.y; qT += t[j] * t[j];
        }
    }

    float cS = dS / fmaxf(sqrtf(qS) * nrm[0][k], EPS_COS);
    float cT = dT / fmaxf(sqrtf(qT) * nrm[1][k], EPS_COS);
    float e = cS - cT;
    float val = e * e;

    for (int off = 32; off; off >>= 1) val += __shfl_down(val, off);
    int lane = tid & 63, wid = tid >> 6;
    if (lane == 0) red[wid] = val;
    __syncthreads();
    if (tid == 0) {
        float blk = 0.0f;
#pragma unroll
        for (int w = 0; w < 16; ++w) blk += red[w];
        atomicAdd(&ws[OFF_LOSS], blk);
        __threadfence();
        int prev = atomicAdd(reinterpret_cast<int*>(ws) + OFF_TICKET, 1);
        if (prev == (int)(gridDim.x * gridDim.y) - 1) {
            float total = atomicAdd(&ws[OFF_LOSS], 0.0f);   // coherent read
            out[0] = total * (1.0f / (float)(B * V));
        }
    }
}

extern "C" void kernel_launch(void* const* d_in, const int* in_sizes, int n_in,
                              void* d_out, int out_size, void* d_ws, size_t ws_size,
                              hipStream_t stream) {
    const float* fS  = (const float*)d_in[0];
    const float* fT  = (const float*)d_in[1];
    const int*   tgt = (const int*)d_in[2];
    float* out = (float*)d_out;
    float* ws  = (float*)d_ws;

    sums_kernel<<<dim3(8, B * C), 512, 0, stream>>>(fS, fT, tgt, ws);
    loss_kernel<<<dim3(V / 1024, B), 1024, 0, stream>>>(fS, fT, tgt, ws, out);
}

// Round 12
// 53.127 us; speedup vs baseline: 1.0319x; 1.0319x over previous
//
#include <hip/hip_runtime.h>
#include <math.h>

#define NUM_CLASSES 5
constexpr int B = 2, C = 64, D = 32, H = 64, W = 64;
constexpr int V = D * H * W;          // 131072
constexpr int TD = 16, TH = 32, TW = 32;
constexpr int TVOX = TD * TH * TW;    // 16384
constexpr float EPS_COS = 1e-8f;

typedef float f32x4 __attribute__((ext_vector_type(4)));
typedef float f32x2 __attribute__((ext_vector_type(2)));

// workspace layout (float offsets). Sums slotted per q-octant:
// ((b*K+k)*C+c)*8+q — plain stores, no zeroing. Counts cancel in cosine.
constexpr int OFF_SUMS_S = 0;                      // 640*8
constexpr int OFF_SUMS_T = 5120;                   // 640*8
constexpr int OFF_LOSS   = 10240;
constexpr int OFF_TICKET = 10241;                  // int (zeroed by sums)
constexpr int WS_FLOATS  = 10256;

// MALL-split strategy (r12): fS is read CACHED in pass 1 (allocates ~67MB
// into the 256MB MALL; caps at ~3 TB/s but overlaps fT's nt stream), so
// pass 2 reads fS WARM (~6.7 TB/s measured r0-r3) and only fT cold-nt.
// fT stays nt in both passes (never allocates). Measured rates: cached cold
// 3.0 / nt cold 5.4-5.8 / warm 6.7 / write 6.9 TB/s.
__device__ __forceinline__ f32x4 ntload4(const float* p) {
    return __builtin_nontemporal_load(reinterpret_cast<const f32x4*>(p));
}
__device__ __forceinline__ f32x2 ntload2(const float* p) {
    return __builtin_nontemporal_load(reinterpret_cast<const f32x2*>(p));
}

// per-(b,c) per-class sums. grid: (8, B*C) = 1024 blocks, 512 threads,
// 4 blocks/CU (32 waves/CU). Geometry FROZEN from r10; fS loads now cached.
__global__ __launch_bounds__(512, 8) void sums_kernel(
    const float* __restrict__ fS, const float* __restrict__ fT,
    const int* __restrict__ tgt, float* __restrict__ ws)
{
    const int bc = blockIdx.y;           // 0..127
    const int b = bc >> 6, c = bc & 63;
    const int q = blockIdx.x;            // octant 0..7
    const int tid = threadIdx.x;         // 0..511

    float accS[NUM_CLASSES] = {0, 0, 0, 0, 0};
    float accT[NUM_CLASSES] = {0, 0, 0, 0, 0};

#pragma unroll
    for (int it = 0; it < 2; ++it) {     // 8192 voxels = one tz plane each
        const int* tb = tgt + b * TVOX + (q * 2 + it) * (TH * TW) + (tid & 15) * 2;
        int2 L0 = *reinterpret_cast<const int2*>(tb + (tid >> 5) * TW);
        int2 L1 = *reinterpret_cast<const int2*>(tb + (16 + (tid >> 5)) * TW);

        const long base = (long)bc * V + q * 16384 + it * 8192 + tid * 4;
        // fS: CACHED loads (allocate into MALL for pass 2)
        f32x4 s0 = *reinterpret_cast<const f32x4*>(fS + base);
        f32x4 s1 = *reinterpret_cast<const f32x4*>(fS + base + 2048);
        f32x4 s2 = *reinterpret_cast<const f32x4*>(fS + base + 4096);
        f32x4 s3 = *reinterpret_cast<const f32x4*>(fS + base + 6144);
        // fT: nt loads (never allocate)
        f32x4 t0 = ntload4(fT + base);
        f32x4 t1 = ntload4(fT + base + 2048);
        f32x4 t2 = ntload4(fT + base + 4096);
        f32x4 t3 = ntload4(fT + base + 6144);

        float sA01 = (s0.x + s0.y) + (s2.x + s2.y), sA23 = (s0.z + s0.w) + (s2.z + s2.w);
        float sB01 = (s1.x + s1.y) + (s3.x + s3.y), sB23 = (s1.z + s1.w) + (s3.z + s3.w);
        float tA01 = (t0.x + t0.y) + (t2.x + t2.y), tA23 = (t0.z + t0.w) + (t2.z + t2.w);
        float tB01 = (t1.x + t1.y) + (t3.x + t3.y), tB23 = (t1.z + t1.w) + (t3.z + t3.w);
#pragma unroll
        for (int k = 0; k < NUM_CLASSES; ++k) {     // static indices only
            accS[k] += ((L0.x == k) ? sA01 : 0.0f) + ((L0.y == k) ? sA23 : 0.0f)
                     + ((L1.x == k) ? sB01 : 0.0f) + ((L1.y == k) ? sB23 : 0.0f);
            accT[k] += ((L0.x == k) ? tA01 : 0.0f) + ((L0.y == k) ? tA23 : 0.0f)
                     + ((L1.x == k) ? tB01 : 0.0f) + ((L1.y == k) ? tB23 : 0.0f);
        }
    }

    __shared__ float wsum[8][2 * NUM_CLASSES];
    int lane = tid & 63, wid = tid >> 6;
#pragma unroll
    for (int k = 0; k < NUM_CLASSES; ++k) {
        float vS = accS[k], vT = accT[k];
        for (int off = 32; off; off >>= 1) {
            vS += __shfl_down(vS, off);
            vT += __shfl_down(vT, off);
        }
        if (lane == 0) { wsum[wid][k] = vS; wsum[wid][NUM_CLASSES + k] = vT; }
    }
    __syncthreads();
    if (tid < 2 * NUM_CLASSES) {
        float v = 0.0f;
#pragma unroll
        for (int w = 0; w < 8; ++w) v += wsum[w][tid];
        int k = tid % NUM_CLASSES;
        int base = (tid < NUM_CLASSES) ? OFF_SUMS_S : OFF_SUMS_T;
        ws[base + ((b * NUM_CLASSES + k) * C + c) * 8 + q] = v;   // slotted store
    }
    // zero LOSS + ticket for the (stream-ordered) loss pass
    if (q == 0 && bc == 0 && tid >= 2 * NUM_CLASSES && tid < 2 * NUM_CLASSES + 2)
        ws[OFF_LOSS + (tid - 2 * NUM_CLASSES)] = 0.0f;
}

// per-voxel cosine + loss reduce + finalize. Shape = r8's proven 512thr x
// 2vox, 1024-voxel window, a[8]/t[8] batches. fS loads cached (MALL-warm
// from pass 1), fT loads nt (cold).
__global__ __launch_bounds__(512) void loss_kernel(
    const float* __restrict__ fS, const float* __restrict__ fT,
    const int* __restrict__ tgt, float* __restrict__ ws, float* __restrict__ out)
{
    __shared__ float mST[C * NUM_CLASSES * 2];   // [c][k][{S,T}] raw sums
    __shared__ float nrm[2][8];
    __shared__ float red[8];
    int tid = threadIdx.x;
    int b = blockIdx.y;

    for (int i = tid; i < C * NUM_CLASSES; i += 512) {
        int c = i / NUM_CLASSES, k = i % NUM_CLASSES;
        int wi = ((b * NUM_CLASSES + k) * C + c) * 8;
        float sS = 0.0f, sT = 0.0f;
#pragma unroll
        for (int qq = 0; qq < 8; ++qq) {
            sS += ws[OFF_SUMS_S + wi + qq];
            sT += ws[OFF_SUMS_T + wi + qq];
        }
        mST[i * 2]     = sS;
        mST[i * 2 + 1] = sT;
    }
    __syncthreads();
    if (tid < 2 * NUM_CLASSES) {                 // 10 center-direction norms
        int k = tid % NUM_CLASSES;
        int st = tid / NUM_CLASSES;              // 0=S, 1=T
        float s = 0.0f;
        for (int c = 0; c < C; ++c) { float v = mST[(c * NUM_CLASSES + k) * 2 + st]; s += v * v; }
        nrm[st][k] = sqrtf(s);
    }
    __syncthreads();

    int v = blockIdx.x * 1024 + tid * 2;         // even voxel pair (shared label)
    int z = v >> 12, y = (v >> 6) & 63, x = v & 63;
    int k = tgt[b * TVOX + (z >> 1) * (TH * TW) + (y >> 1) * TW + (x >> 1)];

    const float* pS = fS + (long)b * C * V + v;
    const float* pT = fT + (long)b * C * V + v;
    float d0S = 0, d1S = 0, q0S = 0, q1S = 0;
    float d0T = 0, d1T = 0, q0T = 0, q1T = 0;

    for (int cb = 0; cb < C; cb += 8) {
        f32x2 a[8], t[8];
#pragma unroll
        for (int j = 0; j < 8; ++j) a[j] = *reinterpret_cast<const f32x2*>(pS + (long)(cb + j) * V);  // warm
#pragma unroll
        for (int j = 0; j < 8; ++j) t[j] = ntload2(pT + (long)(cb + j) * V);                          // cold nt
#pragma unroll
        for (int j = 0; j < 8; ++j) {
            float2 m = *reinterpret_cast<const float2*>(&mST[((cb + j) * NUM_CLASSES + k) * 2]);
            d0S += a[j].x * m.x; d1S += a[j].y * m.x;
            q0S += a[j].x * a[j].x; q1S += a[j].y * a[j].y;
            d0T += t[j].x * m.y; d1T += t[j].y * m.y;
            q0T += t[j].x * t[j].x; q1T += t[j].y * t[j].y;
        }
    }

    float c0S = d0S / fmaxf(sqrtf(q0S) * nrm[0][k], EPS_COS);
    float c1S = d1S / fmaxf(sqrtf(q1S) * nrm[0][k], EPS_COS);
    float c0T = d0T / fmaxf(sqrtf(q0T) * nrm[1][k], EPS_COS);
    float c1T = d1T / fmaxf(sqrtf(q1T) * nrm[1][k], EPS_COS);
    float e0 = c0S - c0T, e1 = c1S - c1T;
    float val = e0 * e0 + e1 * e1;

    for (int off = 32; off; off >>= 1) val += __shfl_down(val, off);
    int lane = tid & 63, wid = tid >> 6;
    if (lane == 0) red[wid] = val;
    __syncthreads();
    if (tid == 0) {
        float blk = 0.0f;
#pragma unroll
        for (int w = 0; w < 8; ++w) blk += red[w];
        atomicAdd(&ws[OFF_LOSS], blk);
        __threadfence();
        int prev = atomicAdd(reinterpret_cast<int*>(ws) + OFF_TICKET, 1);
        if (prev == (int)(gridDim.x * gridDim.y) - 1) {
            float total = atomicAdd(&ws[OFF_LOSS], 0.0f);   // coherent read
            out[0] = total * (1.0f / (float)(B * V));
        }
    }
}

extern "C" void kernel_launch(void* const* d_in, const int* in_sizes, int n_in,
                              void* d_out, int out_size, void* d_ws, size_t ws_size,
                              hipStream_t stream) {
    const float* fS  = (const float*)d_in[0];
    const float* fT  = (const float*)d_in[1];
    const int*   tgt = (const int*)d_in[2];
    float* out = (float*)d_out;
    float* ws  = (float*)d_ws;

    sums_kernel<<<dim3(8, B * C), 512, 0, stream>>>(fS, fT, tgt, ws);
    loss_kernel<<<dim3(V / 1024, B), 512, 0, stream>>>(fS, fT, tgt, ws, out);
}